// Round 5
// baseline (411.841 us; speedup 1.0000x reference)
//
#include <hip/hip_runtime.h>
#include <hip/hip_cooperative_groups.h>
#include <cmath>

namespace cg = cooperative_groups;

constexpr int ISIZE = 512;
constexpr int REC   = 1024;
constexpr int NACT  = 18;
constexpr int BS    = 64;
constexpr float CLIPVAL = 2.0f;
constexpr int NSLOT = 17;  // 16 hebb i-chunk partials + 1 x@W0^T partial

typedef float f4 __attribute__((ext_vector_type(4)));

__device__ __forceinline__ f4 nt_load(const f4* p) {
#if __has_builtin(__builtin_nontemporal_load)
  return __builtin_nontemporal_load(p);
#else
  return *p;
#endif
}
__device__ __forceinline__ void nt_store(f4* p, f4 v) {
#if __has_builtin(__builtin_nontemporal_store)
  __builtin_nontemporal_store(v, p);
#else
  *p = v;
#endif
}

// ===========================================================================
// Fused cooperative kernel: 576 blocks x 256 threads, all co-resident
// (launch_bounds (256,3): <=170 VGPR -> 3 blocks/CU, 768 >= 576).
// Phase A: blocks 0..511 hebb partials (R3-proven layout), 512..575 x@W0^T.
// Phase B: blocks 0..63 per-batch head.
// Phase C: blocks 0..511 re-read the SAME hebb slice (L3-hot) and update.
// ===========================================================================
__global__ __launch_bounds__(256, 3) void k_fused(
    const float* __restrict__ rv, const float* __restrict__ hebb,
    const float* __restrict__ w, const float* __restrict__ alpha,
    const float* __restrict__ x, const float* __restrict__ W0,
    const float* __restrict__ b0, const float* __restrict__ W1,
    const float* __restrict__ b1, const float* __restrict__ h2w,
    const float* __restrict__ h2b, const float* __restrict__ mw,
    const float* __restrict__ mb, float* __restrict__ part,
    float* __restrict__ g, float* __restrict__ hact,
    float* __restrict__ act_dis, float* __restrict__ out) {
  cg::grid_group grid = cg::this_grid();
  const int id = blockIdx.x;
  const int t  = threadIdx.x;

  __shared__ float rvs[4][64];      // persists A -> C
  __shared__ float w0s[32][33];
  __shared__ float xs2[32][33];
  __shared__ float hsh[REC];
  __shared__ float logits_s[32];
  __shared__ float myeta_s;

  // ------------------------------------------------------------- phase A
  if (id < 512) {
    const int bg = id & 15;          // fastest: 16 blocks share w/alpha slice
    const int jh = (id >> 4) & 1;
    const int ic = id >> 5;
    const int b0i = bg * 4, i0 = ic * 64;
    const int jl = t & 127, bl = t >> 7;
    const int j0 = jh * 512 + jl * 4;
    const int ba = b0i + bl * 2;

    rvs[t >> 6][t & 63] = rv[(size_t)(b0i + (t >> 6)) * REC + i0 + (t & 63)];
    __syncthreads();

    f4 a0 = {0.f, 0.f, 0.f, 0.f}, a1 = {0.f, 0.f, 0.f, 0.f};
    const float* __restrict__ wp  = w     + (size_t)i0 * REC + j0;
    const float* __restrict__ ap  = alpha + (size_t)i0 * REC + j0;
    const float* __restrict__ hp0 = hebb + ((size_t)ba * REC + i0) * REC + j0;
    const float* __restrict__ hp1 = hp0 + (size_t)REC * REC;
    const float* __restrict__ r0s = &rvs[bl * 2][0];
    const float* __restrict__ r1s = &rvs[bl * 2 + 1][0];

#pragma unroll 4
    for (int ii = 0; ii < 64; ++ii) {
      const f4 wv = *(const f4*)(wp  + (size_t)ii * REC);
      const f4 av = *(const f4*)(ap  + (size_t)ii * REC);
      const f4 h0 = *(const f4*)(hp0 + (size_t)ii * REC);
      const f4 h1 = *(const f4*)(hp1 + (size_t)ii * REC);
      const float r0 = r0s[ii], r1 = r1s[ii];
      a0.x = fmaf(r0, fmaf(av.x, h0.x, wv.x), a0.x);
      a0.y = fmaf(r0, fmaf(av.y, h0.y, wv.y), a0.y);
      a0.z = fmaf(r0, fmaf(av.z, h0.z, wv.z), a0.z);
      a0.w = fmaf(r0, fmaf(av.w, h0.w, wv.w), a0.w);
      a1.x = fmaf(r1, fmaf(av.x, h1.x, wv.x), a1.x);
      a1.y = fmaf(r1, fmaf(av.y, h1.y, wv.y), a1.y);
      a1.z = fmaf(r1, fmaf(av.z, h1.z, wv.z), a1.z);
      a1.w = fmaf(r1, fmaf(av.w, h1.w, wv.w), a1.w);
    }
    *(f4*)(part + ((size_t)ba * NSLOT + ic) * REC + j0)       = a0;
    *(f4*)(part + ((size_t)(ba + 1) * NSLOT + ic) * REC + j0) = a1;
  } else {
    // x @ W0^T -> part slot 16 (LDS-tiled, coalesced)
    const int idx = id - 512;
    const int jt = idx & 31, bg2 = idx >> 5;
    const int J0 = jt * 32, B0 = bg2 * 32;
    const int tx = t & 31, ty = t >> 5;
    float acc[4] = {0.f, 0.f, 0.f, 0.f};
    for (int kk = 0; kk < ISIZE; kk += 32) {
#pragma unroll
      for (int r = 0; r < 32; r += 8) {
        w0s[tx][ty + r] = W0[(size_t)(J0 + ty + r) * ISIZE + kk + tx];
        xs2[ty + r][tx] = x [(size_t)(B0 + ty + r) * ISIZE + kk + tx];
      }
      __syncthreads();
#pragma unroll
      for (int k = 0; k < 32; ++k) {
        const float w0v = w0s[k][tx];
#pragma unroll
        for (int q = 0; q < 4; ++q)
          acc[q] = fmaf(xs2[ty * 4 + q][k], w0v, acc[q]);
      }
      __syncthreads();
    }
#pragma unroll
    for (int q = 0; q < 4; ++q)
      part[((size_t)(B0 + ty * 4 + q) * NSLOT + 16) * REC + J0 + tx] = acc[q];
  }

  __threadfence();
  grid.sync();

  // ------------------------------------------------------------- phase B
  if (id < BS) {
    const int b = id;
    const int j0 = t * 4;

    f4 s = *(const f4*)(b0 + j0);
#pragma unroll
    for (int sl = 0; sl < NSLOT; ++sl) {
      const f4 p = *(const f4*)(part + ((size_t)b * NSLOT + sl) * REC + j0);
      s.x += p.x; s.y += p.y; s.z += p.z; s.w += p.w;
    }
    f4 h4;
    h4.x = tanhf(s.x); h4.y = tanhf(s.y); h4.z = tanhf(s.z); h4.w = tanhf(s.w);
    *(f4*)(hact + (size_t)b * REC + j0) = h4;
    *(f4*)(&hsh[j0]) = h4;
    __syncthreads();

    const int wid = t >> 6, ln = t & 63;
    for (int a = wid; a < NACT; a += 4) {
      const float* __restrict__ w1a = W1 + (size_t)a * REC;
      float p = 0.f;
#pragma unroll
      for (int c = 0; c < 16; ++c) p = fmaf(hsh[c * 64 + ln], w1a[c * 64 + ln], p);
#pragma unroll
      for (int off = 32; off; off >>= 1) p += __shfl_down(p, off);
      if (ln == 0) logits_s[a] = p + b1[a];
    }
    if (wid == 3) {
      float p = 0.f;
#pragma unroll
      for (int c = 0; c < 16; ++c) p = fmaf(hsh[c * 64 + ln], h2w[c * 64 + ln], p);
#pragma unroll
      for (int off = 32; off; off >>= 1) p += __shfl_down(p, off);
      if (ln == 0) myeta_s = tanhf(p + h2b[0]);
    }
    __syncthreads();

    if (t == 0) {
      float m = logits_s[0];
      for (int a = 1; a < NACT; ++a) m = fmaxf(m, logits_s[a]);
      float e[NACT];
      float ssum = 0.f;
      for (int a = 0; a < NACT; ++a) { e[a] = expf(logits_s[a] - m); ssum += e[a]; }
      const float inv = 1.f / ssum;
      for (int a = 0; a < NACT; ++a) act_dis[(size_t)b * NACT + a] = e[a] * inv;
    }
    __syncthreads();

    const float me = myeta_s;
    const f4 mwv = *(const f4*)(mw + j0);
    const f4 mbv = *(const f4*)(mb + j0);
    const f4 hh  = *(const f4*)(&hsh[j0]);
    f4 gv;
    gv.x = fmaf(me, mwv.x, mbv.x) * hh.x;
    gv.y = fmaf(me, mwv.y, mbv.y) * hh.y;
    gv.z = fmaf(me, mwv.z, mbv.z) * hh.z;
    gv.w = fmaf(me, mwv.w, mbv.w) * hh.w;
    *(f4*)(g + (size_t)b * REC + j0) = gv;
  }

  __threadfence();
  grid.sync();

  // ------------------------------------------------------------- phase C
  if (id < 512) {
    const int bg = id & 15;
    const int jh = (id >> 4) & 1;
    const int ic = id >> 5;
    const int b0i = bg * 4, i0 = ic * 64;
    const int jl = t & 127, bl = t >> 7;
    const int j0 = jh * 512 + jl * 4;
    const int ba = b0i + bl * 2;

    const f4 g0 = *(const f4*)(g + (size_t)ba * REC + j0);
    const f4 g1 = *(const f4*)(g + (size_t)(ba + 1) * REC + j0);
    const float* __restrict__ r0s = &rvs[bl * 2][0];      // still valid
    const float* __restrict__ r1s = &rvs[bl * 2 + 1][0];
    const float* __restrict__ hp0 = hebb + ((size_t)ba * REC + i0) * REC + j0;
    const float* __restrict__ hp1 = hp0 + (size_t)REC * REC;
    float* __restrict__ op0 = out + ((size_t)ba * REC + i0) * REC + j0;
    float* __restrict__ op1 = op0 + (size_t)REC * REC;

#pragma unroll 4
    for (int ii = 0; ii < 64; ++ii) {
      const f4 h0 = *(const f4*)(hp0 + (size_t)ii * REC);
      const f4 h1 = *(const f4*)(hp1 + (size_t)ii * REC);
      const float r0 = r0s[ii], r1 = r1s[ii];
      f4 o0, o1;
      o0.x = fminf(fmaxf(fmaf(r0, g0.x, h0.x), -CLIPVAL), CLIPVAL);
      o0.y = fminf(fmaxf(fmaf(r0, g0.y, h0.y), -CLIPVAL), CLIPVAL);
      o0.z = fminf(fmaxf(fmaf(r0, g0.z, h0.z), -CLIPVAL), CLIPVAL);
      o0.w = fminf(fmaxf(fmaf(r0, g0.w, h0.w), -CLIPVAL), CLIPVAL);
      o1.x = fminf(fmaxf(fmaf(r1, g1.x, h1.x), -CLIPVAL), CLIPVAL);
      o1.y = fminf(fmaxf(fmaf(r1, g1.y, h1.y), -CLIPVAL), CLIPVAL);
      o1.z = fminf(fmaxf(fmaf(r1, g1.z, h1.z), -CLIPVAL), CLIPVAL);
      o1.w = fminf(fmaxf(fmaf(r1, g1.w, h1.w), -CLIPVAL), CLIPVAL);
      nt_store((f4*)(op0 + (size_t)ii * REC), o0);
      nt_store((f4*)(op1 + (size_t)ii * REC), o1);
    }
  }
}

// ===========================================================================
// Fallback: R3's proven 3-kernel path (used only if cooperative launch fails)
// ===========================================================================
__global__ __launch_bounds__(256) void k_pass1_fb(
    const float* __restrict__ rv, const float* __restrict__ hebb,
    const float* __restrict__ w, const float* __restrict__ alpha,
    const float* __restrict__ x, const float* __restrict__ W0,
    float* __restrict__ part) {
  const int id = blockIdx.x;
  const int t  = threadIdx.x;
  if (id < 512) {
    const int bg = id & 15;
    const int jh = (id >> 4) & 1;
    const int ic = id >> 5;
    const int b0 = bg * 4, i0 = ic * 64;
    const int jl = t & 127, bl = t >> 7;
    const int j0 = jh * 512 + jl * 4;
    const int ba = b0 + bl * 2;
    __shared__ float rvs[4][64];
    rvs[t >> 6][t & 63] = rv[(size_t)(b0 + (t >> 6)) * REC + i0 + (t & 63)];
    __syncthreads();
    f4 a0 = {0.f, 0.f, 0.f, 0.f}, a1 = {0.f, 0.f, 0.f, 0.f};
    const float* __restrict__ wp  = w     + (size_t)i0 * REC + j0;
    const float* __restrict__ ap  = alpha + (size_t)i0 * REC + j0;
    const float* __restrict__ hp0 = hebb + ((size_t)ba * REC + i0) * REC + j0;
    const float* __restrict__ hp1 = hp0 + (size_t)REC * REC;
#pragma unroll 4
    for (int ii = 0; ii < 64; ++ii) {
      const f4 wv = *(const f4*)(wp  + (size_t)ii * REC);
      const f4 av = *(const f4*)(ap  + (size_t)ii * REC);
      const f4 h0 = *(const f4*)(hp0 + (size_t)ii * REC);
      const f4 h1 = *(const f4*)(hp1 + (size_t)ii * REC);
      const float r0 = rvs[bl * 2][ii], r1 = rvs[bl * 2 + 1][ii];
      a0.x = fmaf(r0, fmaf(av.x, h0.x, wv.x), a0.x);
      a0.y = fmaf(r0, fmaf(av.y, h0.y, wv.y), a0.y);
      a0.z = fmaf(r0, fmaf(av.z, h0.z, wv.z), a0.z);
      a0.w = fmaf(r0, fmaf(av.w, h0.w, wv.w), a0.w);
      a1.x = fmaf(r1, fmaf(av.x, h1.x, wv.x), a1.x);
      a1.y = fmaf(r1, fmaf(av.y, h1.y, wv.y), a1.y);
      a1.z = fmaf(r1, fmaf(av.z, h1.z, wv.z), a1.z);
      a1.w = fmaf(r1, fmaf(av.w, h1.w, wv.w), a1.w);
    }
    *(f4*)(part + ((size_t)ba * NSLOT + ic) * REC + j0)       = a0;
    *(f4*)(part + ((size_t)(ba + 1) * NSLOT + ic) * REC + j0) = a1;
  } else {
    const int idx = id - 512;
    const int jt = idx & 31, bg2 = idx >> 5;
    const int J0 = jt * 32, B0 = bg2 * 32;
    const int tx = t & 31, ty = t >> 5;
    __shared__ float w0s[32][33];
    __shared__ float xs[32][33];
    float acc[4] = {0.f, 0.f, 0.f, 0.f};
    for (int kk = 0; kk < ISIZE; kk += 32) {
#pragma unroll
      for (int r = 0; r < 32; r += 8) {
        w0s[tx][ty + r] = W0[(size_t)(J0 + ty + r) * ISIZE + kk + tx];
        xs[ty + r][tx]  = x [(size_t)(B0 + ty + r) * ISIZE + kk + tx];
      }
      __syncthreads();
#pragma unroll
      for (int k = 0; k < 32; ++k) {
        const float w0v = w0s[k][tx];
#pragma unroll
        for (int q = 0; q < 4; ++q)
          acc[q] = fmaf(xs[ty * 4 + q][k], w0v, acc[q]);
      }
      __syncthreads();
    }
#pragma unroll
    for (int q = 0; q < 4; ++q)
      part[((size_t)(B0 + ty * 4 + q) * NSLOT + 16) * REC + J0 + tx] = acc[q];
  }
}

__global__ __launch_bounds__(1024) void k_head_fb(
    const float* __restrict__ part, const float* __restrict__ b0,
    const float* __restrict__ W1, const float* __restrict__ b1,
    const float* __restrict__ h2w, const float* __restrict__ h2b,
    const float* __restrict__ mw, const float* __restrict__ mb,
    float* __restrict__ hact, float* __restrict__ act_dis,
    float* __restrict__ g) {
  const int b = blockIdx.x;
  const int t = threadIdx.x;
  __shared__ float hsh[REC];
  __shared__ float logits_s[32];
  __shared__ float myeta_s;
  float s = b0[t];
  const float* __restrict__ pb = part + (size_t)b * NSLOT * REC + t;
#pragma unroll
  for (int sl = 0; sl < NSLOT; ++sl) s += pb[(size_t)sl * REC];
  const float h = tanhf(s);
  hact[(size_t)b * REC + t] = h;
  hsh[t] = h;
  __syncthreads();
  const int wv = t >> 6, ln = t & 63;
  for (int a = wv; a < NACT; a += 16) {
    const float* __restrict__ w1a = W1 + (size_t)a * REC;
    float p = 0.f;
#pragma unroll
    for (int c = 0; c < 16; ++c) p = fmaf(hsh[c * 64 + ln], w1a[c * 64 + ln], p);
#pragma unroll
    for (int off = 32; off; off >>= 1) p += __shfl_down(p, off);
    if (ln == 0) logits_s[a] = p + b1[a];
  }
  if (wv == 0) {
    float p = 0.f;
#pragma unroll
    for (int c = 0; c < 16; ++c) p = fmaf(hsh[c * 64 + ln], h2w[c * 64 + ln], p);
#pragma unroll
    for (int off = 32; off; off >>= 1) p += __shfl_down(p, off);
    if (ln == 0) myeta_s = tanhf(p + h2b[0]);
  }
  __syncthreads();
  if (t == 0) {
    float m = logits_s[0];
    for (int a = 1; a < NACT; ++a) m = fmaxf(m, logits_s[a]);
    float e[NACT];
    float ssum = 0.f;
    for (int a = 0; a < NACT; ++a) { e[a] = expf(logits_s[a] - m); ssum += e[a]; }
    const float inv = 1.f / ssum;
    for (int a = 0; a < NACT; ++a) act_dis[(size_t)b * NACT + a] = e[a] * inv;
  }
  __syncthreads();
  const float me = myeta_s;
  g[(size_t)b * REC + t] = fmaf(me, mw[t], mb[t]) * hsh[t];
}

__global__ __launch_bounds__(256) void k_hebb_fb(
    const float* __restrict__ hebb, const float* __restrict__ rv,
    const float* __restrict__ g, float* __restrict__ out) {
  const int b  = 63 - (int)blockIdx.x;
  const int i0 = (127 - (int)blockIdx.y) * 8;
  const int j0 = threadIdx.x * 4;
  const f4 gv = *(const f4*)(g + (size_t)b * REC + j0);
  const float* __restrict__ rvb = rv + (size_t)b * REC;
  const size_t base = ((size_t)b * REC + i0) * REC + j0;
#pragma unroll
  for (int ii = 0; ii < 8; ++ii) {
    const float r = rvb[i0 + ii];
    const f4 hv = nt_load((const f4*)(hebb + base + (size_t)ii * REC));
    f4 o;
    o.x = fminf(fmaxf(fmaf(r, gv.x, hv.x), -CLIPVAL), CLIPVAL);
    o.y = fminf(fmaxf(fmaf(r, gv.y, hv.y), -CLIPVAL), CLIPVAL);
    o.z = fminf(fmaxf(fmaf(r, gv.z, hv.z), -CLIPVAL), CLIPVAL);
    o.w = fminf(fmaxf(fmaf(r, gv.w, hv.w), -CLIPVAL), CLIPVAL);
    nt_store((f4*)(out + base + (size_t)ii * REC), o);
  }
}

// ---------------------------------------------------------------------------
extern "C" void kernel_launch(void* const* d_in, const int* in_sizes, int n_in,
                              void* d_out, int out_size, void* d_ws, size_t ws_size,
                              hipStream_t stream) {
  const float* x     = (const float*)d_in[0];
  const float* rv    = (const float*)d_in[1];
  const float* hebb  = (const float*)d_in[2];
  const float* w     = (const float*)d_in[3];
  const float* alpha = (const float*)d_in[4];
  const float* W0    = (const float*)d_in[5];
  const float* b0    = (const float*)d_in[6];
  const float* W1    = (const float*)d_in[7];
  const float* b1    = (const float*)d_in[8];
  const float* h2w   = (const float*)d_in[9];
  const float* h2b   = (const float*)d_in[10];
  const float* mw    = (const float*)d_in[11];
  const float* mb    = (const float*)d_in[12];

  float* out_act  = (float*)d_out;               // 64*18
  float* out_hact = out_act + (size_t)BS * NACT; // 64*1024
  float* out_hebb = out_hact + (size_t)BS * REC; // 64*1024*1024

  float* part = (float*)d_ws;                    // 64*17*1024
  float* g    = part + (size_t)BS * NSLOT * REC; // 64*1024

  void* args[] = {(void*)&rv,  (void*)&hebb, (void*)&w,   (void*)&alpha,
                  (void*)&x,   (void*)&W0,   (void*)&b0,  (void*)&W1,
                  (void*)&b1,  (void*)&h2w,  (void*)&h2b, (void*)&mw,
                  (void*)&mb,  (void*)&part, (void*)&g,   (void*)&out_hact,
                  (void*)&out_act, (void*)&out_hebb};
  hipError_t err = hipLaunchCooperativeKernel(k_fused, dim3(576), dim3(256),
                                              args, 0, stream);
  if (err != hipSuccess) {
    // fallback: proven 3-kernel schedule
    k_pass1_fb<<<576, 256, 0, stream>>>(rv, hebb, w, alpha, x, W0, part);
    k_head_fb<<<BS, 1024, 0, stream>>>(part, b0, W1, b1, h2w, h2b, mw, mb,
                                       out_hact, out_act, g);
    k_hebb_fb<<<dim3(64, 128), 256, 0, stream>>>(hebb, rv, g, out_hebb);
  }
}

// Round 6
// 164.631 us; speedup vs baseline: 2.5016x; 2.5016x over previous
//
#include <hip/hip_runtime.h>
#include <cmath>

constexpr int ISIZE = 512;
constexpr int REC   = 1024;
constexpr int NACT  = 18;
constexpr int BS    = 64;
constexpr float CLIPVAL = 2.0f;
constexpr int NSLOT = 17;   // 16 hebb i-chunk partials + 1 x@W0^T partial
constexpr int GB    = 32;   // batches per group: hebb slice 132 MB < L3
constexpr int NGR   = BS / GB;  // 2 groups

typedef float f4 __attribute__((ext_vector_type(4)));

__device__ __forceinline__ void nt_store(f4* p, f4 v) {
#if __has_builtin(__builtin_nontemporal_store)
  __builtin_nontemporal_store(v, p);
#else
  *p = v;
#endif
}

// ---------------------------------------------------------------------------
// Pass 1 for one 32-batch group: 288 blocks.
//   id 0..255 : hebb partials. (ic, jh, bg): 64 i-rows x 512 j x 4 batches;
//               thread: 4 j x 2 batches. bg fastest -> concurrent blocks share
//               each w/alpha slice.
//   id 256..287: x @ W0^T (32x32 LDS-tiled) -> part slot 16.
__global__ __launch_bounds__(256) void k_pass1(
    const float* __restrict__ rv, const float* __restrict__ hebb,
    const float* __restrict__ w, const float* __restrict__ alpha,
    const float* __restrict__ x, const float* __restrict__ W0,
    float* __restrict__ part, int gbase) {
  const int id = blockIdx.x;
  const int t  = threadIdx.x;

  if (id < 256) {
    const int bg = id & 7;           // 8 batch-groups x 4 batches = 32
    const int jh = (id >> 3) & 1;
    const int ic = id >> 4;          // 0..15
    const int b0i = gbase + bg * 4, i0 = ic * 64;
    const int jl = t & 127, bl = t >> 7;
    const int j0 = jh * 512 + jl * 4;
    const int ba = b0i + bl * 2;

    __shared__ float rvs[4][64];
    rvs[t >> 6][t & 63] = rv[(size_t)(b0i + (t >> 6)) * REC + i0 + (t & 63)];
    __syncthreads();

    f4 a0 = {0.f, 0.f, 0.f, 0.f}, a1 = {0.f, 0.f, 0.f, 0.f};
    const float* __restrict__ wp  = w     + (size_t)i0 * REC + j0;
    const float* __restrict__ ap  = alpha + (size_t)i0 * REC + j0;
    const float* __restrict__ hp0 = hebb + ((size_t)ba * REC + i0) * REC + j0;
    const float* __restrict__ hp1 = hp0 + (size_t)REC * REC;
    const float* __restrict__ r0s = &rvs[bl * 2][0];
    const float* __restrict__ r1s = &rvs[bl * 2 + 1][0];

#pragma unroll 4
    for (int ii = 0; ii < 64; ++ii) {
      const f4 wv = *(const f4*)(wp  + (size_t)ii * REC);
      const f4 av = *(const f4*)(ap  + (size_t)ii * REC);
      const f4 h0 = *(const f4*)(hp0 + (size_t)ii * REC);
      const f4 h1 = *(const f4*)(hp1 + (size_t)ii * REC);
      const float r0 = r0s[ii], r1 = r1s[ii];
      a0.x = fmaf(r0, fmaf(av.x, h0.x, wv.x), a0.x);
      a0.y = fmaf(r0, fmaf(av.y, h0.y, wv.y), a0.y);
      a0.z = fmaf(r0, fmaf(av.z, h0.z, wv.z), a0.z);
      a0.w = fmaf(r0, fmaf(av.w, h0.w, wv.w), a0.w);
      a1.x = fmaf(r1, fmaf(av.x, h1.x, wv.x), a1.x);
      a1.y = fmaf(r1, fmaf(av.y, h1.y, wv.y), a1.y);
      a1.z = fmaf(r1, fmaf(av.z, h1.z, wv.z), a1.z);
      a1.w = fmaf(r1, fmaf(av.w, h1.w, wv.w), a1.w);
    }
    *(f4*)(part + ((size_t)ba * NSLOT + ic) * REC + j0)       = a0;
    *(f4*)(part + ((size_t)(ba + 1) * NSLOT + ic) * REC + j0) = a1;

  } else {
    // x @ W0^T for this group's 32 batches -> part slot 16
    const int jt = id - 256;             // 32 j-tiles
    const int J0 = jt * 32, B0 = gbase;  // 32 batches
    const int tx = t & 31, ty = t >> 5;
    __shared__ float w0s[32][33];
    __shared__ float xs[32][33];
    float acc[4] = {0.f, 0.f, 0.f, 0.f};
    for (int kk = 0; kk < ISIZE; kk += 32) {
#pragma unroll
      for (int r = 0; r < 32; r += 8) {
        w0s[tx][ty + r] = W0[(size_t)(J0 + ty + r) * ISIZE + kk + tx];
        xs[ty + r][tx]  = x [(size_t)(B0 + ty + r) * ISIZE + kk + tx];
      }
      __syncthreads();
#pragma unroll
      for (int k = 0; k < 32; ++k) {
        const float w0v = w0s[k][tx];
#pragma unroll
        for (int q = 0; q < 4; ++q)
          acc[q] = fmaf(xs[ty * 4 + q][k], w0v, acc[q]);
      }
      __syncthreads();
    }
#pragma unroll
    for (int q = 0; q < 4; ++q)
      part[((size_t)(B0 + ty * 4 + q) * NSLOT + 16) * REC + J0 + tx] = acc[q];
  }
}

// ---------------------------------------------------------------------------
// Per-batch head (GB blocks x 1024 threads, t == j): reduce 17 partials + b0
// -> tanh -> hactiv; logits; myeta; softmax; g.
__global__ __launch_bounds__(1024) void k_head(
    const float* __restrict__ part, const float* __restrict__ b0,
    const float* __restrict__ W1, const float* __restrict__ b1,
    const float* __restrict__ h2w, const float* __restrict__ h2b,
    const float* __restrict__ mw, const float* __restrict__ mb,
    float* __restrict__ hact, float* __restrict__ act_dis,
    float* __restrict__ g, int gbase) {
  const int b = gbase + blockIdx.x;
  const int t = threadIdx.x;
  __shared__ float hsh[REC];
  __shared__ float logits_s[32];
  __shared__ float myeta_s;

  float s = b0[t];
  const float* __restrict__ pb = part + (size_t)b * NSLOT * REC + t;
#pragma unroll
  for (int sl = 0; sl < NSLOT; ++sl) s += pb[(size_t)sl * REC];
  const float h = tanhf(s);
  hact[(size_t)b * REC + t] = h;
  hsh[t] = h;
  __syncthreads();

  const int wv = t >> 6, ln = t & 63;
  for (int a = wv; a < NACT; a += 16) {
    const float* __restrict__ w1a = W1 + (size_t)a * REC;
    float p = 0.f;
#pragma unroll
    for (int c = 0; c < 16; ++c) p = fmaf(hsh[c * 64 + ln], w1a[c * 64 + ln], p);
#pragma unroll
    for (int off = 32; off; off >>= 1) p += __shfl_down(p, off);
    if (ln == 0) logits_s[a] = p + b1[a];
  }
  if (wv == 0) {
    float p = 0.f;
#pragma unroll
    for (int c = 0; c < 16; ++c) p = fmaf(hsh[c * 64 + ln], h2w[c * 64 + ln], p);
#pragma unroll
    for (int off = 32; off; off >>= 1) p += __shfl_down(p, off);
    if (ln == 0) myeta_s = tanhf(p + h2b[0]);
  }
  __syncthreads();

  if (t == 0) {
    float m = logits_s[0];
    for (int a = 1; a < NACT; ++a) m = fmaxf(m, logits_s[a]);
    float e[NACT];
    float ssum = 0.f;
    for (int a = 0; a < NACT; ++a) { e[a] = expf(logits_s[a] - m); ssum += e[a]; }
    const float inv = 1.f / ssum;
    for (int a = 0; a < NACT; ++a) act_dis[(size_t)b * NACT + a] = e[a] * inv;
  }
  __syncthreads();
  const float me = myeta_s;
  g[(size_t)b * REC + t] = fmaf(me, mw[t], mb[t]) * hsh[t];
}

// ---------------------------------------------------------------------------
// Pass 2 for one group: hebb_out = clip(hebb + rv[b,i]*g[b,j]).
// Natural order (matches pass-1's streaming order); hebb loads should hit L3
// (slice was just read by pass-1, flow-through < L3 size). nt stores keep the
// write stream from evicting the resident slice.
__global__ __launch_bounds__(256) void k_hebb(
    const float* __restrict__ hebb, const float* __restrict__ rv,
    const float* __restrict__ g, float* __restrict__ out, int gbase) {
  const int b  = gbase + blockIdx.x;
  const int i0 = blockIdx.y * 8;
  const int j0 = threadIdx.x * 4;
  const f4 gv = *(const f4*)(g + (size_t)b * REC + j0);
  const float* __restrict__ rvb = rv + (size_t)b * REC;
  const size_t base = ((size_t)b * REC + i0) * REC + j0;
#pragma unroll
  for (int ii = 0; ii < 8; ++ii) {
    const float r = rvb[i0 + ii];
    const f4 hv = *(const f4*)(hebb + base + (size_t)ii * REC);
    f4 o;
    o.x = fminf(fmaxf(fmaf(r, gv.x, hv.x), -CLIPVAL), CLIPVAL);
    o.y = fminf(fmaxf(fmaf(r, gv.y, hv.y), -CLIPVAL), CLIPVAL);
    o.z = fminf(fmaxf(fmaf(r, gv.z, hv.z), -CLIPVAL), CLIPVAL);
    o.w = fminf(fmaxf(fmaf(r, gv.w, hv.w), -CLIPVAL), CLIPVAL);
    nt_store((f4*)(out + base + (size_t)ii * REC), o);
  }
}

// ---------------------------------------------------------------------------
extern "C" void kernel_launch(void* const* d_in, const int* in_sizes, int n_in,
                              void* d_out, int out_size, void* d_ws, size_t ws_size,
                              hipStream_t stream) {
  const float* x     = (const float*)d_in[0];
  const float* rv    = (const float*)d_in[1];
  const float* hebb  = (const float*)d_in[2];
  const float* w     = (const float*)d_in[3];
  const float* alpha = (const float*)d_in[4];
  const float* W0    = (const float*)d_in[5];
  const float* b0    = (const float*)d_in[6];
  const float* W1    = (const float*)d_in[7];
  const float* b1    = (const float*)d_in[8];
  const float* h2w   = (const float*)d_in[9];
  const float* h2b   = (const float*)d_in[10];
  const float* mw    = (const float*)d_in[11];
  const float* mb    = (const float*)d_in[12];

  float* out_act  = (float*)d_out;               // 64*18
  float* out_hact = out_act + (size_t)BS * NACT; // 64*1024
  float* out_hebb = out_hact + (size_t)BS * REC; // 64*1024*1024

  float* part = (float*)d_ws;                    // 64*17*1024
  float* g    = part + (size_t)BS * NSLOT * REC; // 64*1024

  for (int grp = 0; grp < NGR; ++grp) {
    const int gbase = grp * GB;
    k_pass1<<<288, 256, 0, stream>>>(rv, hebb, w, alpha, x, W0, part, gbase);
    k_head<<<GB, 1024, 0, stream>>>(part, b0, W1, b1, h2w, h2b, mw, mb,
                                    out_hact, out_act, g, gbase);
    k_hebb<<<dim3(GB, 128), 256, 0, stream>>>(hebb, rv, g, out_hebb, gbase);
  }
}